// Round 9
// baseline (887.140 us; speedup 1.0000x reference)
//
#include <hip/hip_runtime.h>

// LSTM feedback net: B=16384, T=48 warmup, F=4, UNITS=256, 24 AR steps.
// R9: de-phased waves. The barrier serialized gate-VALU (~4.9us) behind the
// GEMM phase (~4.1us, MFMA+L2-stream overlapped). Tile t is produced by wave
// t>>1 only, so wave w consumes tiles in rotated order (2w, 2w+1, ..., 16)
// and syncs via per-wave LDS flags instead of s_barrier:
//   F[8]: h^(s+1) written (post after gates), P[8]: step-s reads done,
//   X[2]: x/pred cols written. Producer overwrites a buffer parity only
//   after all P >= s (skew < 2 steps; protects pred reads transitively).
// Gate phase of lagging waves overlaps MFMA/L2 of leading waves (m114).
// Tile 17 (all zero) dropped: 17 K-tiles. Gates/layouts unchanged from R8.

typedef unsigned short u16;
typedef __attribute__((ext_vector_type(8))) short bf16x8;
typedef __attribute__((ext_vector_type(16))) float f32x16;

#define PITCH 296    // hext row pitch, elems (592 B/row)
#define HB 18944     // elems per h buffer (64*296)
#define WARM 48
#define STEPS 71     // 48 warmup + 23 AR cell steps
#define LOG2E  1.442695041f
#define LOG2E2 2.885390082f

__device__ __forceinline__ u16 f2bf(float f) {
    unsigned u = __float_as_uint(f);
    u += 0x7FFFu + ((u >> 16) & 1u);   // round-to-nearest-even
    return (u16)(u >> 16);
}

// LDS-only barrier for init phase.
__device__ __forceinline__ void sync_lds() {
    asm volatile("s_waitcnt lgkmcnt(0)\n\ts_barrier" ::: "memory");
}

__device__ __forceinline__ void wait_ge(int* f, int target) {
    while (__hip_atomic_load(f, __ATOMIC_ACQUIRE, __HIP_MEMORY_SCOPE_WORKGROUP) < target)
        __builtin_amdgcn_s_sleep(1);
}
// release store: s_waitcnt lgkmcnt(0) drains the whole wave's LDS ops first
__device__ __forceinline__ void post(int* f, int v, int lane) {
    if (lane == 0)
        __hip_atomic_store(f, v, __ATOMIC_RELEASE, __HIP_MEMORY_SCOPE_WORKGROUP);
}

// ---- prep (unchanged from R8): 32x32x16 A-fragments of W' (K=288 x N=1024).
// Frag (kt,g,wv): lane l, j=0..7 holds W'[kt*16+(l>>5)*8+j][256g+32wv+(l&31)].
// K rows: 0..255 Wh, 256..259 Wx, 260 bias. Cols scaled log2e / 2log2e (g).
__global__ void prep_weights(const float* __restrict__ Wx,
                             const float* __restrict__ Wh,
                             const float* __restrict__ b,
                             const float* __restrict__ Wd,
                             const float* __restrict__ bd,
                             u16* __restrict__ whext,
                             u16* __restrict__ wdp) {
    int idx = blockIdx.x * 256 + threadIdx.x;   // one thread per 16B chunk
    if (idx < 36864) {                          // 18 kt * 4 g * 8 wv * 64 lanes
        int lane = idx & 63;
        int frag = idx >> 6;
        int wv = frag & 7;
        int g = (frag >> 3) & 3;
        int kt = frag >> 5;
        int k0 = kt * 16 + (lane >> 5) * 8;
        int n = 256 * g + 32 * wv + (lane & 31);
        float sc = (g == 2) ? LOG2E2 : LOG2E;
        u16 v[8];
#pragma unroll
        for (int j = 0; j < 8; ++j) {
            int k = k0 + j;
            float f = 0.0f;
            if (k < 256) f = Wh[k * 1024 + n];
            else if (k < 260) f = Wx[(k - 256) * 1024 + n];
            else if (k == 260) f = b[n];
            v[j] = f2bf(f * sc);
        }
        ushort4* dst = (ushort4*)(whext + (size_t)idx * 8);
        dst[0] = make_ushort4(v[0], v[1], v[2], v[3]);
        dst[1] = make_ushort4(v[4], v[5], v[6], v[7]);
    } else if (idx < 36864 + 1152) {            // Wd: 18 frags x 64 lanes
        int id2 = idx - 36864;
        int lane = id2 & 63;
        int kt = id2 >> 6;
        int k0 = kt * 16 + (lane >> 5) * 8;
        int f_ = lane & 31;
        u16 v[8];
#pragma unroll
        for (int j = 0; j < 8; ++j) {
            int k = k0 + j;
            float f = 0.0f;
            if (f_ < 4) {
                if (k < 256) f = Wd[k * 4 + f_];
                else if (k == 260) f = bd[f_];
            }
            v[j] = f2bf(f);
        }
        ushort4* dst = (ushort4*)(wdp + (size_t)id2 * 8);
        dst[0] = make_ushort4(v[0], v[1], v[2], v[3]);
        dst[1] = make_ushort4(v[4], v[5], v[6], v[7]);
    }
}

#define WLOADT(DST, T) do {                                                   \
    const char* _wk = wp + ((size_t)(T) << 15);                               \
    _Pragma("unroll") for (int g = 0; g < 4; ++g)                             \
        DST[g] = *(const bf16x8*)(_wk + voff[g]);                             \
} while (0)

#define HLOADT(DST, T) do {                                                   \
    DST[0] = *(const bf16x8*)&hr[hrow0 + (T) * 16];                           \
    DST[1] = *(const bf16x8*)&hr[hrow1 + (T) * 16];                           \
} while (0)

#define MT(WA, HBX)                                                           \
    _Pragma("unroll") for (int m = 0; m < 2; ++m)                             \
    _Pragma("unroll") for (int g = 0; g < 4; ++g)                             \
        acc[m][g] = __builtin_amdgcn_mfma_f32_32x32x16_bf16(                  \
            WA[g], HBX[m], acc[m][g], 0, 0, 0);

// guard the prefetch of rotation index I (tile (2w+I)&15, or 16 = x/bias)
#define GUARD(I) do {                                                         \
    if ((I) < 16) wait_ge(&Ff[((2 * w + (I)) & 15) >> 1], step);              \
    else { wait_ge(&Xf[0], step); wait_ge(&Xf[1], step); }                    \
} while (0)

__global__ __launch_bounds__(512, 2) void lstm_main(
    const float* __restrict__ x, const u16* __restrict__ whext,
    const u16* __restrict__ wdp, float* __restrict__ out) {
    __shared__ __align__(16) unsigned char smem[75904];
    u16* hbuf = (u16*)smem;                  // 2 x 18944 elems bf16 (75776 B)
    int* Ff = (int*)(smem + 75776);          // F[8] | P[8] | X[2]
    int* Pf = Ff + 8;
    int* Xf = Ff + 16;

    const int tid = threadIdx.x;
    const int w = tid >> 6;        // wave 0..7 -> units [32w, 32w+32)
    const int l = tid & 63;
    const int l31 = l & 31;
    const int lh = l >> 5;
    const long long rowBase = (long long)blockIdx.x * 64;

    {   // zero h buffers + flags
        int4 z = make_int4(0, 0, 0, 0);
        for (int i = tid; i < 4744; i += 512) ((int4*)smem)[i] = z;
    }
    sync_lds();
    if (tid < 64) {
        hbuf[tid * PITCH + 260] = (u16)0x3F80;        // bias-1 col, buffer 0
        hbuf[HB + tid * PITCH + 260] = (u16)0x3F80;   // and buffer 1
        const float4 xv = *(const float4*)(x + (rowBase + tid) * 192);
        u16* p = &hbuf[tid * PITCH + 256];             // x_0 -> buffer 0
        p[0] = f2bf(xv.x); p[1] = f2bf(xv.y); p[2] = f2bf(xv.z); p[3] = f2bf(xv.w);
    }
    sync_lds();   // init state visible to all waves; from here on: flags only

    const char* __restrict__ wp = (const char*)whext;
    const char* __restrict__ dp = (const char*)wdp;
    int voff[4];
#pragma unroll
    for (int g = 0; g < 4; ++g) voff[g] = ((g * 8 + w) * 64 + l) * 16;
    const int hrow0 = l31 * PITCH + lh * 8;          // B-frag row, m=0 (elems)
    const int hrow1 = (32 + l31) * PITCH + lh * 8;   // m=1
    const int t0 = 2 * w, t1 = 2 * w + 1;            // own tiles (no flag wait)

    f32x16 c[2] = {};      // cell state: m -> batch 32m+l31; reg r -> unit
                           // 32w + (r&3) + 8*(r>>2) + 4*lh
    bf16x8 awA[4], awB[4], awC[4];
    WLOADT(awA, t0);       // weights are step-invariant: preload own tiles
    WLOADT(awB, t1);

    for (int step = 0; step < STEPS; ++step) {
        const u16* hr = hbuf + (step & 1) * HB;      // h^(step)
        u16* hw = hbuf + ((step & 1) ^ 1) * HB;      // h^(step+1) (overwrites h^(step-1))

        f32x16 acc[2][4] = {};   // [batch-tile m][gate]
        bf16x8 hbA[2], hbB[2], hbC[2];
        HLOADT(hbA, t0);         // own h tiles: written by own gates last step
        HLOADT(hbB, t1);

        // rotated K-loop: index i -> tile (2w+i)&15 for i<16, tile 16 last
#pragma unroll 1
        for (int i = 0; i < 15; i += 3) {
            GUARD(i + 2); { int t = (2 * w + i + 2) & 15; WLOADT(awC, t); HLOADT(hbC, t); }
            MT(awA, hbA);                          // rot i
            GUARD(i + 3); { int t = (2 * w + i + 3) & 15; WLOADT(awA, t); HLOADT(hbA, t); }
            MT(awB, hbB);                          // rot i+1
            { int i4 = i + 4; GUARD(i4); int t = (i4 < 16) ? ((2 * w + i4) & 15) : 16;
              WLOADT(awB, t); HLOADT(hbB, t); }
            MT(awC, hbC);                          // rot i+2
        }
        post(Pf + w, step + 1, l);   // all step-s h reads done (release drains lgkm)
        MT(awA, hbA);                // rot 15
        WLOADT(awA, t0);             // next step's weights fly over gate phase
        MT(awB, hbB);                // rot 16 (x/bias tile)
        WLOADT(awB, t1);

        // before overwriting h^(step-1) parity: all consumers must be done
#pragma unroll 1
        for (int c2 = 0; c2 < 8; ++c2) wait_ge(Pf + c2, step);

        // gates; lane holds batch 32m+l31, units 32w + (r&3)+8*(r>>2)+4*lh
#pragma unroll
        for (int m = 0; m < 2; ++m) {
            const int hwrow = (32 * m + l31) * PITCH + 32 * w + 4 * lh;
#pragma unroll
            for (int q = 0; q < 4; ++q) {
                u16 hh[4];
#pragma unroll
                for (int rr = 0; rr < 4; ++rr) {
                    const int r = q * 4 + rr;
                    float ei = __builtin_amdgcn_exp2f(-acc[m][0][r]);
                    float ef = __builtin_amdgcn_exp2f(-acc[m][1][r]);
                    float eg = __builtin_amdgcn_exp2f(-acc[m][2][r]);
                    float eo = __builtin_amdgcn_exp2f(-acc[m][3][r]);
                    float fv  = __builtin_amdgcn_rcpf(1.0f + ef);
                    float rig = __builtin_amdgcn_rcpf((1.0f + ei) * (1.0f + eg));
                    float cn  = c[m][r] * fv + (1.0f - eg) * rig;
                    c[m][r] = cn;
                    float ec = __builtin_amdgcn_exp2f(-LOG2E2 * cn);
                    float roc = __builtin_amdgcn_rcpf((1.0f + eo) * (1.0f + ec));
                    hh[rr] = f2bf((1.0f - ec) * roc);
                }
                *(ushort4*)&hw[hwrow + 8 * q] = make_ushort4(hh[0], hh[1], hh[2], hh[3]);
            }
        }
        post(Ff + w, step + 1, l);   // h^(step+1) units [32w,32w+32) ready

        if (step < WARM - 1) {
            if (w == 0) {   // x_{step+1} -> hw cols 256..259 (consumed at rot 16)
                const float4 xv = *(const float4*)(x + (rowBase + l) * 192 + (step + 1) * 4);
                u16* p = &hw[l * PITCH + 256];
                p[0] = f2bf(xv.x); p[1] = f2bf(xv.y); p[2] = f2bf(xv.z); p[3] = f2bf(xv.w);
                post(Xf + 0, step + 1, l);
                post(Xf + 1, step + 1, l);
            }
        } else {
            if (w < 2) {   // pred^T = Wd'^T @ h^(step+1)^T ; wave w -> batch-tile w
#pragma unroll 1
                for (int p2 = 0; p2 < 8; ++p2) wait_ge(Ff + p2, step + 1);
                f32x16 pacc = {};
                const int prow = (32 * w + l31) * PITCH + lh * 8;
#pragma unroll
                for (int kt = 0; kt < 17; ++kt) {   // tile 17 is all-zero: skip
                    bf16x8 hbp = *(const bf16x8*)&hw[prow + kt * 16];
                    bf16x8 wap = *(const bf16x8*)(dp + ((size_t)kt * 64 + l) * 16);
                    pacc = __builtin_amdgcn_mfma_f32_32x32x16_bf16(wap, hbp, pacc, 0, 0, 0);
                }
                if (lh == 0) {   // regs 0..3 = the 4 features of batch 32w+l31
                    int s = step - (WARM - 1);
                    int batch = 32 * w + l31;
                    *(float4*)&out[((rowBase + batch) * 24 + s) * 4] =
                        make_float4(pacc[0], pacc[1], pacc[2], pacc[3]);
                    *(ushort4*)&hw[batch * PITCH + 256] =   // feed back as x_{step+1}
                        make_ushort4(f2bf(pacc[0]), f2bf(pacc[1]), f2bf(pacc[2]), f2bf(pacc[3]));
                }
                post(Xf + w, step + 1, l);
            }
        }
    }
}

extern "C" void kernel_launch(void* const* d_in, const int* in_sizes, int n_in,
                              void* d_out, int out_size, void* d_ws, size_t ws_size,
                              hipStream_t stream) {
    const float* x  = (const float*)d_in[0];   // [16384,48,4]
    const float* Wx = (const float*)d_in[1];   // [4,1024]
    const float* Wh = (const float*)d_in[2];   // [256,1024]
    const float* b  = (const float*)d_in[3];   // [1024]
    const float* Wd = (const float*)d_in[4];   // [256,4]
    const float* bd = (const float*)d_in[5];   // [4]
    float* out = (float*)d_out;                // [16384,24,4] fp32

    u16* whext = (u16*)d_ws;                        // 589824 B
    u16* wdp = (u16*)((char*)d_ws + 589824);        // 18432 B

    prep_weights<<<(36864 + 1152 + 255) / 256, 256, 0, stream>>>(Wx, Wh, b, Wd, bd, whext, wdp);
    lstm_main<<<256, 512, 0, stream>>>(x, whext, wdp, out);
}

// Round 10
// 751.121 us; speedup vs baseline: 1.1811x; 1.1811x over previous
//
#include <hip/hip_runtime.h>

// LSTM feedback net: B=16384, T=48 warmup, F=4, UNITS=256, 24 AR steps.
// R10: phase-locked (R9 flags failed: P-wait re-syncs everything), 32x32
// layout from R8 (7.6x fewer bank conflicts, c in regs), 2-deep A/B ring
// from R6/R7 (R8's 3-ring regressed). VALU cuts, the dominant cost
// (~5.5us/step, 61% transcendental):
//  - 8->7 trans/elem: cn via single common-denominator rcp.
//  - v_cvt_pk_bf16_f32 for all f32->bf16 packing (1 instr / 2 elems).
//  - drop all-zero K-tile 17 (17 tiles: -5.5% MFMA + weight stream).
//  - wave0 x-prefetch issued at step top (10us before use).

typedef unsigned short u16;
typedef __attribute__((ext_vector_type(8))) short bf16x8;
typedef __attribute__((ext_vector_type(16))) float f32x16;

#define PITCH 296    // hext row pitch, elems (592 B/row)
#define HB 18944     // elems per h buffer (64*296)
#define WARM 48
#define STEPS 71     // 48 warmup + 23 AR cell steps
#define LOG2E  1.442695041f
#define LOG2E2 2.885390082f

__device__ __forceinline__ u16 f2bf(float f) {
    unsigned u = __float_as_uint(f);
    u += 0x7FFFu + ((u >> 16) & 1u);   // round-to-nearest-even
    return (u16)(u >> 16);
}

// pack 2 f32 -> 2 bf16 (RNE), one VOP3 instr (gfx942+)
__device__ __forceinline__ unsigned pk_bf16(float a, float b) {
    unsigned d;
    asm("v_cvt_pk_bf16_f32 %0, %1, %2" : "=v"(d) : "v"(a), "v"(b));
    return d;
}

// LDS-only barrier: drain LDS ops, NOT vmcnt -> global loads stay in flight.
__device__ __forceinline__ void sync_lds() {
    asm volatile("s_waitcnt lgkmcnt(0)\n\ts_barrier" ::: "memory");
}

// ---- prep (R8 layout): 32x32x16 A-fragments of W' (K=288 x N=1024).
// Frag (kt,g,wv): lane l, j=0..7 holds W'[kt*16+(l>>5)*8+j][256g+32wv+(l&31)].
// K rows: 0..255 Wh, 256..259 Wx, 260 bias. Cols scaled log2e / 2log2e (g).
__global__ void prep_weights(const float* __restrict__ Wx,
                             const float* __restrict__ Wh,
                             const float* __restrict__ b,
                             const float* __restrict__ Wd,
                             const float* __restrict__ bd,
                             u16* __restrict__ whext,
                             u16* __restrict__ wdp) {
    int idx = blockIdx.x * 256 + threadIdx.x;   // one thread per 16B chunk
    if (idx < 36864) {                          // 18 kt * 4 g * 8 wv * 64 lanes
        int lane = idx & 63;
        int frag = idx >> 6;
        int wv = frag & 7;
        int g = (frag >> 3) & 3;
        int kt = frag >> 5;
        int k0 = kt * 16 + (lane >> 5) * 8;
        int n = 256 * g + 32 * wv + (lane & 31);
        float sc = (g == 2) ? LOG2E2 : LOG2E;
        u16 v[8];
#pragma unroll
        for (int j = 0; j < 8; ++j) {
            int k = k0 + j;
            float f = 0.0f;
            if (k < 256) f = Wh[k * 1024 + n];
            else if (k < 260) f = Wx[(k - 256) * 1024 + n];
            else if (k == 260) f = b[n];
            v[j] = f2bf(f * sc);
        }
        ushort4* dst = (ushort4*)(whext + (size_t)idx * 8);
        dst[0] = make_ushort4(v[0], v[1], v[2], v[3]);
        dst[1] = make_ushort4(v[4], v[5], v[6], v[7]);
    } else if (idx < 36864 + 1152) {            // Wd: 18 frags x 64 lanes
        int id2 = idx - 36864;
        int lane = id2 & 63;
        int kt = id2 >> 6;
        int k0 = kt * 16 + (lane >> 5) * 8;
        int f_ = lane & 31;
        u16 v[8];
#pragma unroll
        for (int j = 0; j < 8; ++j) {
            int k = k0 + j;
            float f = 0.0f;
            if (f_ < 4) {
                if (k < 256) f = Wd[k * 4 + f_];
                else if (k == 260) f = bd[f_];
            }
            v[j] = f2bf(f);
        }
        ushort4* dst = (ushort4*)(wdp + (size_t)id2 * 8);
        dst[0] = make_ushort4(v[0], v[1], v[2], v[3]);
        dst[1] = make_ushort4(v[4], v[5], v[6], v[7]);
    }
}

#define WLOADT(DST, T) do {                                                   \
    const char* _wk = wp + ((size_t)(T) << 15);                               \
    _Pragma("unroll") for (int g = 0; g < 4; ++g)                             \
        DST[g] = *(const bf16x8*)(_wk + voff[g]);                             \
} while (0)

#define HLOADT(DST, T) do {                                                   \
    DST[0] = *(const bf16x8*)&hr[hrow0 + (T) * 16];                           \
    DST[1] = *(const bf16x8*)&hr[hrow1 + (T) * 16];                           \
} while (0)

#define MT(WA, HBX)                                                           \
    _Pragma("unroll") for (int m = 0; m < 2; ++m)                             \
    _Pragma("unroll") for (int g = 0; g < 4; ++g)                             \
        acc[m][g] = __builtin_amdgcn_mfma_f32_32x32x16_bf16(                  \
            WA[g], HBX[m], acc[m][g], 0, 0, 0);

__global__ __launch_bounds__(512, 2) void lstm_main(
    const float* __restrict__ x, const u16* __restrict__ whext,
    const u16* __restrict__ wdp, float* __restrict__ out) {
    __shared__ __align__(16) u16 hbuf[2 * HB];   // h double buffer only

    const int tid = threadIdx.x;
    const int w = tid >> 6;        // wave 0..7 -> units [32w, 32w+32)
    const int l = tid & 63;
    const int l31 = l & 31;
    const int lh = l >> 5;
    const long long rowBase = (long long)blockIdx.x * 64;

    {   // zero both h buffers (incl. pad cols)
        int4 z = make_int4(0, 0, 0, 0);
        for (int i = tid; i < 4736; i += 512) ((int4*)hbuf)[i] = z;
    }
    sync_lds();
    if (tid < 64) {
        hbuf[tid * PITCH + 260] = (u16)0x3F80;        // bias-1 col, buffer 0
        hbuf[HB + tid * PITCH + 260] = (u16)0x3F80;   // and buffer 1
        const float4 xv = *(const float4*)(x + (rowBase + tid) * 192);
        uint2* p = (uint2*)&hbuf[tid * PITCH + 256];   // x_0 -> buffer 0
        *p = make_uint2(pk_bf16(xv.x, xv.y), pk_bf16(xv.z, xv.w));
    }

    const char* __restrict__ wp = (const char*)whext;
    const char* __restrict__ dp = (const char*)wdp;
    int voff[4];   // per-lane byte offset of frag (kt=0, g, w)
#pragma unroll
    for (int g = 0; g < 4; ++g) voff[g] = ((g * 8 + w) * 64 + l) * 16;
    const int hrow0 = l31 * PITCH + lh * 8;          // B-frag row, m=0 (elems)
    const int hrow1 = (32 + l31) * PITCH + lh * 8;   // m=1

    f32x16 c[2] = {};      // cell state: m -> batch 32m+l31; reg r -> unit
                           // 32w + (r&3) + 8*(r>>2) + 4*lh
    bf16x8 awA[4], awB[4];
    WLOADT(awA, 0);        // in flight across the barrier
    WLOADT(awB, 1);

    for (int step = 0; step < STEPS; ++step) {
        const u16* hr = hbuf + (step & 1) * HB;      // read buffer
        u16* hw = hbuf + ((step & 1) ^ 1) * HB;      // write buffer

        // wave 0: issue next warmup x load NOW; used ~10us later at step end
        float4 xv = make_float4(0.f, 0.f, 0.f, 0.f);
        if (w == 0 && step < WARM - 1)
            xv = *(const float4*)(x + (rowBase + l) * 192 + (step + 1) * 4);

        sync_lds();   // hr ready; prior reads of hw done

        f32x16 acc[2][4] = {};   // [batch-tile m][gate]
        bf16x8 hbA[2], hbB[2];
        HLOADT(hbA, 0);
        HLOADT(hbB, 1);

        // 17 K-tiles (tile 17 all-zero: dropped). 2-deep A/B ring.
#pragma unroll 1
        for (int t = 0; t < 13; t += 2) {
            MT(awA, hbA);                          // tile t
            WLOADT(awA, t + 2); HLOADT(hbA, t + 2);
            MT(awB, hbB);                          // tile t+1
            WLOADT(awB, t + 3); HLOADT(hbB, t + 3);
        }
        MT(awA, hbA);                // tile 14
        WLOADT(awA, 16); HLOADT(hbA, 16);
        MT(awB, hbB);                // tile 15
        WLOADT(awB, 1);              // next-step tile 1 (flies over gates+barrier)
        MT(awA, hbA);                // tile 16 (x/bias)
        WLOADT(awA, 0);              // next-step tile 0

        // gates; lane holds batch 32m+l31, units 32w + (r&3)+8*(r>>2)+4*lh.
        // 7 transcendentals/elem: 5 exp2 + 2 rcp (common-denominator c-update).
#pragma unroll
        for (int m = 0; m < 2; ++m) {
            const int hwrow = (32 * m + l31) * PITCH + 32 * w + 4 * lh;
#pragma unroll
            for (int q = 0; q < 4; ++q) {
                unsigned pk[2];
#pragma unroll
                for (int hp = 0; hp < 2; ++hp) {
                    float h2[2];
#pragma unroll
                    for (int rr = 0; rr < 2; ++rr) {
                        const int r = q * 4 + hp * 2 + rr;
                        float ei = __builtin_amdgcn_exp2f(-acc[m][0][r]);
                        float ef = __builtin_amdgcn_exp2f(-acc[m][1][r]);
                        float eg = __builtin_amdgcn_exp2f(-acc[m][2][r]);
                        float eo = __builtin_amdgcn_exp2f(-acc[m][3][r]);
                        float ai = 1.0f + ei, af = 1.0f + ef;
                        float ag = 1.0f + eg, ao = 1.0f + eo;
                        float P  = ai * ag;
                        float rD = __builtin_amdgcn_rcpf(P * af);
                        float cn = fmaf(c[m][r] * P, rD, (1.0f - eg) * af * rD);
                        c[m][r] = cn;
                        float ec = __builtin_amdgcn_exp2f(-LOG2E2 * cn);
                        float rE = __builtin_amdgcn_rcpf(ao * (1.0f + ec));
                        h2[rr] = (1.0f - ec) * rE;
                    }
                    pk[hp] = pk_bf16(h2[0], h2[1]);
                }
                *(uint2*)&hw[hwrow + 8 * q] = make_uint2(pk[0], pk[1]);
            }
        }

        if (step < WARM - 1) {
            if (w == 0) {   // x_{step+1} (prefetched at step top) -> hw
                uint2* p = (uint2*)&hw[l * PITCH + 256];
                *p = make_uint2(pk_bf16(xv.x, xv.y), pk_bf16(xv.z, xv.w));
            }
        } else {
            sync_lds();        // h_new in hw visible for pred GEMM
            if (w < 2) {       // pred^T = Wd'^T @ h_new^T ; wave w -> batch-tile w
                f32x16 pacc = {};
                const int prow = (32 * w + l31) * PITCH + lh * 8;
#pragma unroll
                for (int kt = 0; kt < 17; ++kt) {
                    bf16x8 hbp = *(const bf16x8*)&hw[prow + kt * 16];
                    bf16x8 wap = *(const bf16x8*)(dp + ((size_t)kt * 64 + l) * 16);
                    pacc = __builtin_amdgcn_mfma_f32_32x32x16_bf16(wap, hbp, pacc, 0, 0, 0);
                }
                if (lh == 0) {   // regs 0..3 = the 4 features of batch 32w+l31
                    int s = step - (WARM - 1);
                    int batch = 32 * w + l31;
                    *(float4*)&out[((rowBase + batch) * 24 + s) * 4] =
                        make_float4(pacc[0], pacc[1], pacc[2], pacc[3]);
                    *(uint2*)&hw[batch * PITCH + 256] =   // feed back as next x_t
                        make_uint2(pk_bf16(pacc[0], pacc[1]), pk_bf16(pacc[2], pacc[3]));
                }
            }
        }
    }
}

extern "C" void kernel_launch(void* const* d_in, const int* in_sizes, int n_in,
                              void* d_out, int out_size, void* d_ws, size_t ws_size,
                              hipStream_t stream) {
    const float* x  = (const float*)d_in[0];   // [16384,48,4]
    const float* Wx = (const float*)d_in[1];   // [4,1024]
    const float* Wh = (const float*)d_in[2];   // [256,1024]
    const float* b  = (const float*)d_in[3];   // [1024]
    const float* Wd = (const float*)d_in[4];   // [256,4]
    const float* bd = (const float*)d_in[5];   // [4]
    float* out = (float*)d_out;                // [16384,24,4] fp32

    u16* whext = (u16*)d_ws;                        // 589824 B
    u16* wdp = (u16*)((char*)d_ws + 589824);        // 18432 B

    prep_weights<<<(36864 + 1152 + 255) / 256, 256, 0, stream>>>(Wx, Wh, b, Wd, bd, whext, wdp);
    lstm_main<<<256, 512, 0, stream>>>(x, whext, wdp, out);
}

// Round 11
// 749.125 us; speedup vs baseline: 1.1842x; 1.0027x over previous
//
#include <hip/hip_runtime.h>

// LSTM feedback net: B=16384, T=48 warmup, F=4, UNITS=256, 24 AR steps.
// R11 = R10 + three phase-locked refinements:
//  - g-contiguous weight layout: frag (kt, w, g) -> per wave one VGPR addr,
//    gate frags at imm offsets {0,1024,2048,3072}, kt stepped via SGPR base.
//  - 3-deep aw prestage: next step's tiles 0,1,2 issued before the gate
//    phase, in flight across the LDS-only barrier (stream head start).
//  - pred tail on 4 waves via mfma 16x16x32 (9 MFMA, pacc 4 regs) instead
//    of 2 waves x 17 MFMA 32x32.
// Invariant: acc 128 (AGPR) + VGPR (aw48+hb16+c32+misc~16) <= 256 -> no spill.

typedef unsigned short u16;
typedef __attribute__((ext_vector_type(8))) short bf16x8;
typedef __attribute__((ext_vector_type(4))) float f32x4;
typedef __attribute__((ext_vector_type(16))) float f32x16;

#define PITCH 296    // hext row pitch, elems (592 B/row)
#define HB 18944     // elems per h buffer (64*296)
#define WARM 48
#define STEPS 71     // 48 warmup + 23 AR cell steps
#define LOG2E  1.442695041f
#define LOG2E2 2.885390082f

__device__ __forceinline__ u16 f2bf(float f) {
    unsigned u = __float_as_uint(f);
    u += 0x7FFFu + ((u >> 16) & 1u);   // round-to-nearest-even
    return (u16)(u >> 16);
}

// pack 2 f32 -> 2 bf16 (RNE), one VOP3 instr
__device__ __forceinline__ unsigned pk_bf16(float a, float b) {
    unsigned d;
    asm("v_cvt_pk_bf16_f32 %0, %1, %2" : "=v"(d) : "v"(a), "v"(b));
    return d;
}

// LDS-only barrier: drain LDS ops, NOT vmcnt -> global loads stay in flight.
__device__ __forceinline__ void sync_lds() {
    asm volatile("s_waitcnt lgkmcnt(0)\n\ts_barrier" ::: "memory");
}

// ---- prep: 32x32x16 A-fragments of W' (K=272 x N=1024), 17 kt tiles.
// NEW frag order: idx = kt*32 + wv*4 + g  (g fastest -> imm-offset loads).
// Lane l of a frag holds W'[kt*16+(l>>5)*8+j][256g+32wv+(l&31)], j=0..7.
// K rows: 0..255 Wh, 256..259 Wx, 260 bias. Cols scaled log2e / 2log2e (g).
// wd16: 9 K32-chunks of Wd^T in 16x16x32 A-layout (m=feature), unscaled.
__global__ void prep_weights(const float* __restrict__ Wx,
                             const float* __restrict__ Wh,
                             const float* __restrict__ b,
                             const float* __restrict__ Wd,
                             const float* __restrict__ bd,
                             u16* __restrict__ whext,
                             u16* __restrict__ wdp) {
    int idx = blockIdx.x * 256 + threadIdx.x;   // one thread per 16B chunk
    if (idx < 34816) {                          // 17 kt * 8 wv * 4 g * 64 lanes
        int lane = idx & 63;
        int fr = idx >> 6;
        int g = fr & 3;
        int wv = (fr >> 2) & 7;
        int kt = fr >> 5;
        int k0 = kt * 16 + (lane >> 5) * 8;
        int n = 256 * g + 32 * wv + (lane & 31);
        float sc = (g == 2) ? LOG2E2 : LOG2E;
        u16 v[8];
#pragma unroll
        for (int j = 0; j < 8; ++j) {
            int k = k0 + j;
            float f = 0.0f;
            if (k < 256) f = Wh[k * 1024 + n];
            else if (k < 260) f = Wx[(k - 256) * 1024 + n];
            else if (k == 260) f = b[n];
            v[j] = f2bf(f * sc);
        }
        ushort4* dst = (ushort4*)(whext + (size_t)idx * 8);
        dst[0] = make_ushort4(v[0], v[1], v[2], v[3]);
        dst[1] = make_ushort4(v[4], v[5], v[6], v[7]);
    } else if (idx < 34816 + 576) {             // wd16: 9 chunks x 64 lanes
        int id2 = idx - 34816;
        int lane = id2 & 63;
        int kc = id2 >> 6;
        int m = lane & 15;                      // feature row
        int k0 = kc * 32 + (lane >> 4) * 8;
        u16 v[8];
#pragma unroll
        for (int j = 0; j < 8; ++j) {
            int k = k0 + j;
            float f = 0.0f;
            if (m < 4) {
                if (k < 256) f = Wd[k * 4 + m];
                else if (k == 260) f = bd[m];
            }
            v[j] = f2bf(f);
        }
        ushort4* dst = (ushort4*)(wdp + (size_t)id2 * 8);
        dst[0] = make_ushort4(v[0], v[1], v[2], v[3]);
        dst[1] = make_ushort4(v[4], v[5], v[6], v[7]);
    }
}

// wave base wpw = whext + w*4096B; per kt stride 32768B; per g imm 1024B.
#define WL(DST, T) do {                                                       \
    const char* _p = wpw + ((size_t)(T) << 15);                               \
    DST[0] = *(const bf16x8*)(_p + voffl);                                    \
    DST[1] = *(const bf16x8*)(_p + voffl + 1024);                             \
    DST[2] = *(const bf16x8*)(_p + voffl + 2048);                             \
    DST[3] = *(const bf16x8*)(_p + voffl + 3072);                             \
} while (0)

#define HL(DST, T) do {                                                       \
    DST[0] = *(const bf16x8*)&hr[hrow0 + (T) * 16];                           \
    DST[1] = *(const bf16x8*)&hr[hrow1 + (T) * 16];                           \
} while (0)

#define MT(WA, HBX)                                                           \
    _Pragma("unroll") for (int m = 0; m < 2; ++m)                             \
    _Pragma("unroll") for (int g = 0; g < 4; ++g)                             \
        acc[m][g] = __builtin_amdgcn_mfma_f32_32x32x16_bf16(                  \
            WA[g], HBX[m], acc[m][g], 0, 0, 0);

// one pipeline stage: consume tile K from (AW,HBX), refill AW<-K+3, HBX<-K+2
#define STG(K, AW, HBX) do { MT(AW, HBX); WL(AW, (K) + 3); HL(HBX, (K) + 2); } while (0)

__global__ __launch_bounds__(512, 2) void lstm_main(
    const float* __restrict__ x, const u16* __restrict__ whext,
    const u16* __restrict__ wdp, float* __restrict__ out) {
    __shared__ __align__(16) u16 hbuf[2 * HB];   // h double buffer

    const int tid = threadIdx.x;
    const int w = tid >> 6;        // wave 0..7 -> units [32w, 32w+32)
    const int l = tid & 63;
    const int l31 = l & 31;
    const int lh = l >> 5;
    const long long rowBase = (long long)blockIdx.x * 64;

    {   // zero both h buffers (incl. pad cols 261..287 -- stay zero forever)
        int4 z = make_int4(0, 0, 0, 0);
        for (int i = tid; i < 4736; i += 512) ((int4*)hbuf)[i] = z;
    }
    sync_lds();
    if (tid < 64) {
        hbuf[tid * PITCH + 260] = (u16)0x3F80;        // bias-1 col, buffer 0
        hbuf[HB + tid * PITCH + 260] = (u16)0x3F80;   // and buffer 1
        const float4 xv = *(const float4*)(x + (rowBase + tid) * 192);
        uint2* p = (uint2*)&hbuf[tid * PITCH + 256];   // x_0 -> buffer 0
        *p = make_uint2(pk_bf16(xv.x, xv.y), pk_bf16(xv.z, xv.w));
    }

    const char* __restrict__ wpw = (const char*)whext + (size_t)w * 4096;
    const char* __restrict__ dp = (const char*)wdp;
    const int voffl = l * 16;
    const int hrow0 = l31 * PITCH + lh * 8;          // B-frag row, m=0 (elems)
    const int hrow1 = (32 + l31) * PITCH + lh * 8;   // m=1

    f32x16 c[2] = {};      // cell state: m -> batch 32m+l31; reg r -> unit
                           // 32w + (r&3) + 8*(r>>2) + 4*lh
    bf16x8 aw0[4], aw1[4], aw2[4];   // 3-ring: tile k lives in aw[k%3]
    WL(aw0, 0);            // in flight across the first barrier
    WL(aw1, 1);
    WL(aw2, 2);

    for (int step = 0; step < STEPS; ++step) {
        const u16* hr = hbuf + (step & 1) * HB;      // read buffer
        u16* hw = hbuf + ((step & 1) ^ 1) * HB;      // write buffer

        // wave 0: issue next warmup x load now; used ~10us later at step end
        float4 xv = make_float4(0.f, 0.f, 0.f, 0.f);
        if (w == 0 && step < WARM - 1)
            xv = *(const float4*)(x + (rowBase + l) * 192 + (step + 1) * 4);

        sync_lds();   // hr ready; prior reads of hw done; aw0..2 in flight

        f32x16 acc[2][4] = {};   // [batch-tile m][gate]
        bf16x8 hb0[2], hb1[2];   // 2-ring: tile k lives in hb[k&1]
        HL(hb0, 0);
        HL(hb1, 1);

        // 17 K-tiles. Stage k: MT(aw[k%3], hb[k&1]); WL<-k+3; HL<-k+2.
        STG(0, aw0, hb0);
        STG(1, aw1, hb1);
#pragma unroll 1
        for (int k = 2; k < 14; k += 6) {   // k = 2..13, fixed slot pattern
            STG(k + 0, aw2, hb0);
            STG(k + 1, aw0, hb1);
            STG(k + 2, aw1, hb0);
            STG(k + 3, aw2, hb1);
            STG(k + 4, aw0, hb0);
            STG(k + 5, aw1, hb1);
        }
        MT(aw2, hb0); WL(aw2, 2); HL(hb0, 16);   // tile 14; prestage next-2
        MT(aw0, hb1); WL(aw0, 0);                // tile 15; prestage next-0
        MT(aw1, hb0); WL(aw1, 1);                // tile 16; prestage next-1
        // aw0..2 now hold NEXT step's tiles 0..2, flying over gates+barrier

        // gates; lane holds batch 32m+l31, units 32w + (r&3)+8*(r>>2)+4*lh.
        // 7 transcendentals/elem: 5 exp2 + 2 rcp.
#pragma unroll
        for (int m = 0; m < 2; ++m) {
            const int hwrow = (32 * m + l31) * PITCH + 32 * w + 4 * lh;
#pragma unroll
            for (int q = 0; q < 4; ++q) {
                unsigned pk[2];
#pragma unroll
                for (int hp = 0; hp < 2; ++hp) {
                    float h2[2];
#pragma unroll
                    for (int rr = 0; rr < 2; ++rr) {
                        const int r = q * 4 + hp * 2 + rr;
                        float ei = __builtin_amdgcn_exp2f(-acc[m][0][r]);
                        float ef = __builtin_amdgcn_exp2f(-acc[m][1][r]);
                        float eg = __builtin_amdgcn_exp2f(-acc[m][2][r]);
                        float eo = __builtin_amdgcn_exp2f(-acc[m][3][r]);
                        float ai = 1.0f + ei, af = 1.0f + ef;
                        float ag = 1.0f + eg, ao = 1.0f + eo;
                        float P  = ai * ag;
                        float rD = __builtin_amdgcn_rcpf(P * af);
                        float cn = fmaf(c[m][r] * P, rD, (1.0f - eg) * af * rD);
                        c[m][r] = cn;
                        float ec = __builtin_amdgcn_exp2f(-LOG2E2 * cn);
                        float rE = __builtin_amdgcn_rcpf(ao * (1.0f + ec));
                        h2[rr] = (1.0f - ec) * rE;
                    }
                    pk[hp] = pk_bf16(h2[0], h2[1]);
                }
                *(uint2*)&hw[hwrow + 8 * q] = make_uint2(pk[0], pk[1]);
            }
        }

        if (step < WARM - 1) {
            if (w == 0) {   // x_{step+1} (prefetched at step top) -> hw
                uint2* p = (uint2*)&hw[l * PITCH + 256];
                *p = make_uint2(pk_bf16(xv.x, xv.y), pk_bf16(xv.z, xv.w));
            }
        } else {
            sync_lds();        // h_new in hw visible for pred GEMM
            if (w < 4) {       // pred on 4 waves, 16x16x32: batch-tile-16 = w
                f32x4 pacc = {};
                const int col = l & 15;                     // batch within tile
                const int prow = (16 * w + col) * PITCH + (l >> 4) * 8;
#pragma unroll
                for (int kc = 0; kc < 9; ++kc) {            // K32 chunks 0..8
                    bf16x8 hbp = *(const bf16x8*)&hw[prow + kc * 32];
                    bf16x8 wap = *(const bf16x8*)(dp + ((size_t)kc * 64 + l) * 16);
                    pacc = __builtin_amdgcn_mfma_f32_16x16x32_bf16(wap, hbp, pacc, 0, 0, 0);
                }
                if ((l >> 4) == 0) {   // quad 0: regs 0..3 = features 0..3
                    int s = step - (WARM - 1);
                    int batch = 16 * w + col;
                    *(float4*)&out[((rowBase + batch) * 24 + s) * 4] =
                        make_float4(pacc[0], pacc[1], pacc[2], pacc[3]);
                    *(uint2*)&hw[batch * PITCH + 256] =   // feed back as next x_t
                        make_uint2(pk_bf16(pacc[0], pacc[1]), pk_bf16(pacc[2], pacc[3]));
                }
            }
        }
    }
}

extern "C" void kernel_launch(void* const* d_in, const int* in_sizes, int n_in,
                              void* d_out, int out_size, void* d_ws, size_t ws_size,
                              hipStream_t stream) {
    const float* x  = (const float*)d_in[0];   // [16384,48,4]
    const float* Wx = (const float*)d_in[1];   // [4,1024]
    const float* Wh = (const float*)d_in[2];   // [256,1024]
    const float* b  = (const float*)d_in[3];   // [1024]
    const float* Wd = (const float*)d_in[4];   // [256,4]
    const float* bd = (const float*)d_in[5];   // [4]
    float* out = (float*)d_out;                // [16384,24,4] fp32

    u16* whext = (u16*)d_ws;                        // 17*32*64*16 = 557056 B
    u16* wdp = (u16*)((char*)d_ws + 557056);        // 9216 B

    prep_weights<<<(34816 + 576 + 255) / 256, 256, 0, stream>>>(Wx, Wh, b, Wd, bd, whext, wdp);
    lstm_main<<<256, 512, 0, stream>>>(x, whext, wdp, out);
}